// Round 6
// baseline (287.155 us; speedup 1.0000x reference)
//
#include <hip/hip_runtime.h>
#include <hip/hip_bf16.h>
#include <cmath>

#define BS 8
#define SEQ 16384
#define D 128
#define NH 8
#define HD 16
#define EPS_ 1e-5f

#define CH 64                       // tokens per chunk
#define NCHK_A 2                    // chunks per passA block -> 1024 blocks
#define BPB_A (SEQ/(CH*NCHK_A))     // 128
#define CPB_B 2                     // chunks per passB block -> 1024 blocks
#define BPB_B (SEQ/(CH*CPB_B))      // 128
#define CPBATCH (SEQ/CH)            // 256 chunks per batch

typedef __attribute__((ext_vector_type(8))) short bf16x8;
typedef __attribute__((ext_vector_type(4))) float f32x4;
typedef __attribute__((ext_vector_type(4))) unsigned int u32x4;
typedef __attribute__((ext_vector_type(2))) unsigned int u32x2;

#define MFMA16(a,b,c) __builtin_amdgcn_mfma_f32_16x16x32_bf16(a,b,c,0,0,0)

__device__ __forceinline__ unsigned short bf16rn(float x){
    union { __hip_bfloat16 h; unsigned short u; } v;
    v.h = __float2bfloat16(x);
    return v.u;
}
__device__ __forceinline__ float bf16tof(unsigned int u16){
    union { unsigned int u; float f; } v;
    v.u = u16 << 16;
    return v.f;
}
__device__ __forceinline__ unsigned int cvt2(float a, float b){
    union { __hip_bfloat162 h; unsigned int u; } v;
    v.h = __float22bfloat162_rn(make_float2(a, b));
    return v.u;
}
// natural [64 tok][128 col] bf16 LDS; XOR-swizzle, 16B granule
__device__ __forceinline__ int swzQ(int tok, int col){ return (tok*128 + col) ^ ((tok&7)<<3); }
// transposed [256 col][64 tok] bf16 LDS
__device__ __forceinline__ int swzT(int col, int tok){ return (col*64 + tok) ^ ((col&7)<<3); }

// ---------------------------------------------------------------------------
// Weight pre-pack: WB (k|v B-frags), WqA (Wq A-frags). 24 blocks.
// ---------------------------------------------------------------------------
__global__ __launch_bounds__(256) void packW(
    const float* __restrict__ Wk, const float* __restrict__ Wv,
    const float* __restrict__ Wq,
    short* __restrict__ WB, short* __restrict__ WqA)
{
    int e = blockIdx.x * 256 + threadIdx.x;     // 0..6143
    short v8[8];
    if (e < 4096) {
        int nt = e >> 8, kt = (e >> 6) & 3, l = e & 63;
        int col = nt * 16 + (l & 15);
        const float* W = (col < 128) ? Wk : Wv;
        int cc = col & 127;
#pragma unroll
        for (int j = 0; j < 8; ++j)
            v8[j] = (short)bf16rn(W[(kt*32 + (l>>4)*8 + j)*D + cc]);
        u32x4 p = u32x4{ (unsigned)(unsigned short)v8[0] | ((unsigned)(unsigned short)v8[1]<<16),
                         (unsigned)(unsigned short)v8[2] | ((unsigned)(unsigned short)v8[3]<<16),
                         (unsigned)(unsigned short)v8[4] | ((unsigned)(unsigned short)v8[5]<<16),
                         (unsigned)(unsigned short)v8[6] | ((unsigned)(unsigned short)v8[7]<<16) };
        *(u32x4*)&WB[((nt*4 + kt)*64 + l)*8] = p;
    } else {
        int e2 = e - 4096;                      // 0..2047
        int mt = e2 >> 8, kt = (e2 >> 6) & 3, l = e2 & 63;
        int m = mt*16 + (l & 15);
#pragma unroll
        for (int j = 0; j < 8; ++j)
            v8[j] = (short)bf16rn(Wq[(kt*32 + (l>>4)*8 + j)*D + m]);
        u32x4 p = u32x4{ (unsigned)(unsigned short)v8[0] | ((unsigned)(unsigned short)v8[1]<<16),
                         (unsigned)(unsigned short)v8[2] | ((unsigned)(unsigned short)v8[3]<<16),
                         (unsigned)(unsigned short)v8[4] | ((unsigned)(unsigned short)v8[5]<<16),
                         (unsigned)(unsigned short)v8[6] | ((unsigned)(unsigned short)v8[7]<<16) };
        *(u32x4*)&WqA[((mt*4 + kt)*64 + l)*8] = p;
    }
}

// ---------------------------------------------------------------------------
// Pass A: k,v,q projections (MFMA, Q-frags shared); phi; KV/Ksum via MFMA;
//         phiq stored to ws in C-layout tiles [chunk][qt][nt][lane] (u32x2).
// ---------------------------------------------------------------------------
__global__ __launch_bounds__(256, 3) void passA(
    const float* __restrict__ Q,
    const float* __restrict__ bk, const float* __restrict__ bv,
    const float* __restrict__ bq,
    const short* __restrict__ WB, const short* __restrict__ WqA,
    float* __restrict__ KV, float* __restrict__ Ksum,
    u32x2* __restrict__ phiq)
{
    __shared__ __align__(16) short Qlds[64*128];   // 16 KB
    __shared__ __align__(16) short TL[256*64];     // 32 KB: [kcol|vcol][tok]

    const int t = threadIdx.x;
    const int w = t >> 6, l = t & 63;
    const int b  = blockIdx.x / BPB_A;
    const int bb = blockIdx.x % BPB_A;
    const long base = (long)b * SEQ + (long)bb * (CH * NCHK_A);

    bf16x8 wb[4][4];
#pragma unroll
    for (int ntl = 0; ntl < 4; ++ntl)
#pragma unroll
        for (int kt = 0; kt < 4; ++kt)
            wb[ntl][kt] = *(const bf16x8*)&WB[(((w*4+ntl)*4 + kt)*64 + l)*8];
    bf16x8 wq[2][4];
#pragma unroll
    for (int m = 0; m < 2; ++m)
#pragma unroll
        for (int kt = 0; kt < 4; ++kt)
            wq[m][kt] = *(const bf16x8*)&WqA[(((w*2+m)*4 + kt)*64 + l)*8];

    float bias[4];
#pragma unroll
    for (int ntl = 0; ntl < 4; ++ntl) {
        int col = (w*4+ntl)*16 + (l & 15);
        bias[ntl] = (col < 128) ? bk[col] : bv[col-128];
    }
    float bqv[2][4];
#pragma unroll
    for (int m = 0; m < 2; ++m)
#pragma unroll
        for (int r = 0; r < 4; ++r)
            bqv[m][r] = bq[(w*2+m)*16 + (l>>4)*4 + r];

    union { u32x4 u; bf16x8 h; } onesu;
    unsigned ov = ((l & 15) == 0) ? 0x3F803F80u : 0u;
    onesu.u = u32x4{ov, ov, ov, ov};
    const bf16x8 bones = onesu.h;

    const int h0 = w * 2;
    const f32x4 z4 = {0.f, 0.f, 0.f, 0.f};
    f32x4 kvacc[2] = {z4, z4};
    f32x4 ksacc[2] = {z4, z4};

    for (int c = 0; c < NCHK_A; ++c) {
        const long tok0 = base + (long)c * CH;
        const int chunkG = b*CPBATCH + bb*NCHK_A + c;

        // --- stage Q chunk -> bf16 LDS ---
#pragma unroll
        for (int i = 0; i < 4; ++i) {
            int lin = i*256 + t;
            int row = lin >> 4;
            int c0  = (lin & 15) * 8;
            const float4* gp = (const float4*)&Q[(tok0 + row)*D + c0];
            float4 a = gp[0], d4 = gp[1];
            u32x4 p = u32x4{cvt2(a.x,a.y), cvt2(a.z,a.w), cvt2(d4.x,d4.y), cvt2(d4.z,d4.w)};
            *(u32x4*)&Qlds[swzQ(row, c0)] = p;
        }
        __syncthreads();                           // bar1: Qlds ready

        // --- per token-tile mt: k|v proj (A=Q), q proj (B=Q, same frags) ---
#pragma unroll
        for (int mt = 0; mt < 4; ++mt) {
            bf16x8 af[4];
#pragma unroll
            for (int kt = 0; kt < 4; ++kt)
                af[kt] = *(bf16x8*)&Qlds[swzQ(mt*16 + (l&15), kt*32 + (l>>4)*8)];
            // k|v: C[tok][outcol]
#pragma unroll
            for (int ntl = 0; ntl < 4; ++ntl) {
                f32x4 acc = f32x4{bias[ntl], bias[ntl], bias[ntl], bias[ntl]};
#pragma unroll
                for (int kt = 0; kt < 4; ++kt)
                    acc = MFMA16(af[kt], wb[ntl][kt], acc);
                int colg = (w*4+ntl)*16 + (l & 15);
                if (colg < 128) {                  // wave-uniform (w<2): phi_k
#pragma unroll
                    for (int r = 0; r < 4; ++r)
                        acc[r] = (acc[r] > 0.f) ? (acc[r] + 1.f) : __expf(acc[r]);
                }
                int tokb = mt*16 + (l>>4)*4;
                u32x2 p = u32x2{cvt2(acc[0], acc[1]), cvt2(acc[2], acc[3])};
                *(u32x2*)&TL[swzT(colg, tokb)] = p;
            }
            // q: swapped, C[qcol][tok]; phi; store bf16 frags to ws
#pragma unroll
            for (int m = 0; m < 2; ++m) {
                f32x4 qa = f32x4{bqv[m][0], bqv[m][1], bqv[m][2], bqv[m][3]};
#pragma unroll
                for (int kt = 0; kt < 4; ++kt)
                    qa = MFMA16(wq[m][kt], af[kt], qa);
                unsigned s[4];
#pragma unroll
                for (int r = 0; r < 4; ++r) {
                    float x = qa[r];
                    x = (x > 0.f) ? (x + 1.f) : __expf(x);
                    s[r] = bf16rn(x);
                }
                phiq[((chunkG*8 + (w*2+m))*4 + mt)*64 + l] =
                    u32x2{ s[0] | (s[1]<<16), s[2] | (s[3]<<16) };
            }
        }
        __syncthreads();                           // bar2: TL ready

        // --- KV & Ksum MFMA (2 heads per wave) ---
#pragma unroll
        for (int hh = 0; hh < 2; ++hh) {
            int h = h0 + hh;
#pragma unroll
            for (int k2 = 0; k2 < 2; ++k2) {
                bf16x8 afk = *(bf16x8*)&TL[swzT(h*16 + (l&15),       k2*32 + (l>>4)*8)];
                bf16x8 bfv = *(bf16x8*)&TL[swzT(128 + h*16 + (l&15), k2*32 + (l>>4)*8)];
                kvacc[hh] = MFMA16(afk, bfv,  kvacc[hh]);
                ksacc[hh] = MFMA16(afk, bones, ksacc[hh]);
            }
        }
    }

#pragma unroll
    for (int hh = 0; hh < 2; ++hh) {
        int h = h0 + hh;
#pragma unroll
        for (int r = 0; r < 4; ++r)
            atomicAdd(&KV[((b*NH + h)*HD + (l>>4)*4 + r)*HD + (l & 15)], kvacc[hh][r]);
        if ((l & 15) == 0) {
#pragma unroll
            for (int r = 0; r < 4; ++r)
                atomicAdd(&Ksum[(b*NH + h)*HD + (l>>4)*4 + r], ksacc[hh][r]);
        }
    }
}

// ---------------------------------------------------------------------------
// packW2: W2[b] = KV[b] . Wo  (fp32 accum, one bf16 rounding), stored as
// A-frags W2A[b][mt][kt][lane][8].  8 blocks (one per batch).
// ---------------------------------------------------------------------------
__global__ __launch_bounds__(256) void packW2(
    const float* __restrict__ Wo, const float* __restrict__ KV,
    short* __restrict__ W2A)
{
    __shared__ float KVs[NH*HD*HD];    // 8 KB
    __shared__ short W2s[128*128];     // 32 KB
    const int b = blockIdx.x, t = threadIdx.x;
    for (int i = t; i < NH*HD*HD; i += 256) KVs[i] = KV[b*NH*HD*HD + i];
    __syncthreads();

    const int qd = t >> 1, half = t & 1;
    const int h = qd >> 4, dd = qd & 15;
    float acc[64];
#pragma unroll
    for (int i = 0; i < 64; ++i) acc[i] = 0.f;
    for (int vc = 0; vc < 16; ++vc) {
        float kvv = KVs[(h*16 + dd)*16 + vc];
        const float* wrow = &Wo[(h*16 + vc)*D + half*64];
#pragma unroll
        for (int i = 0; i < 64; ++i) acc[i] += kvv * wrow[i];
    }
#pragma unroll
    for (int i = 0; i < 64; ++i)
        W2s[qd*128 + half*64 + i] = (short)bf16rn(acc[i]);
    __syncthreads();

    // frag pack: slot = mt*256 + kt*64 + l; 8 slots per thread
#pragma unroll
    for (int s = 0; s < 8; ++s) {
        int slot = t*8 + s;
        int mt = slot >> 8, kt = (slot >> 6) & 3, l = slot & 63;
        unsigned v[8];
#pragma unroll
        for (int j = 0; j < 8; ++j)
            v[j] = (unsigned short)W2s[(kt*32 + (l>>4)*8 + j)*128 + mt*16 + (l&15)];
        u32x4 p = u32x4{ v[0]|(v[1]<<16), v[2]|(v[3]<<16), v[4]|(v[5]<<16), v[6]|(v[7]<<16) };
        *(u32x4*)&W2A[(((b*8 + mt)*4 + kt)*64 + l)*8] = p;
    }
}

// ---------------------------------------------------------------------------
// Pass B: Z from phiq frags (1 shfl), scale, out = phiq~ @ W2 + bo.
// Zero LDS. 1024 blocks x 128 tokens.
// ---------------------------------------------------------------------------
__global__ __launch_bounds__(256, 4) void passB(
    const float* __restrict__ bo,
    const short* __restrict__ W2A, const float* __restrict__ Ksum,
    const u32x2* __restrict__ phiq,
    float* __restrict__ out)
{
    const int t = threadIdx.x;
    const int w = t >> 6, l = t & 63;
    const int b  = blockIdx.x / BPB_B;
    const int cb = blockIdx.x % BPB_B;

    bf16x8 w2[2][4];
#pragma unroll
    for (int m = 0; m < 2; ++m)
#pragma unroll
        for (int kt = 0; kt < 4; ++kt)
            w2[m][kt] = *(const bf16x8*)&W2A[(((b*8 + (w*2+m))*4 + kt)*64 + l)*8];

    float bov[2][4];
#pragma unroll
    for (int m = 0; m < 2; ++m)
#pragma unroll
        for (int r = 0; r < 4; ++r)
            bov[m][r] = bo[(w*2+m)*16 + (l>>4)*4 + r];

    float Ks[4][8];
#pragma unroll
    for (int kt = 0; kt < 4; ++kt) {
        const float* kp = &Ksum[b*D + kt*32 + (l>>4)*8];
        f32x4 k0 = *(const f32x4*)kp;
        f32x4 k1 = *(const f32x4*)(kp + 4);
#pragma unroll
        for (int j = 0; j < 4; ++j) { Ks[kt][j] = k0[j]; Ks[kt][4+j] = k1[j]; }
    }

    const int lnb   = ((l>>4)&1)*32 + (l&15);   // source lane for j0..3
    const int qhalf = (l >= 32) ? 1 : 0;        // which qt of the kt pair

    for (int c = 0; c < CPB_B; ++c) {
        const int chunkG = b*CPBATCH + cb*CPB_B + c;
        const long tokbase = (long)b*SEQ + (long)(cb*CPB_B + c)*CH;

#pragma unroll
        for (int nt = 0; nt < 4; ++nt) {
            bf16x8 bfrag[4];
#pragma unroll
            for (int kt = 0; kt < 4; ++kt) {
                const int slotbase = ((chunkG*8 + 2*kt + qhalf)*4 + nt)*64;
                u32x2 fa = phiq[slotbase + lnb];
                u32x2 fb = phiq[slotbase + lnb + 16];
                float v0 = bf16tof(fa.x & 0xffffu), v1 = bf16tof(fa.x >> 16);
                float v2 = bf16tof(fa.y & 0xffffu), v3 = bf16tof(fa.y >> 16);
                float v4 = bf16tof(fb.x & 0xffffu), v5 = bf16tof(fb.x >> 16);
                float v6 = bf16tof(fb.y & 0xffffu), v7 = bf16tof(fb.y >> 16);
                float s = v0*Ks[kt][0] + v1*Ks[kt][1] + v2*Ks[kt][2] + v3*Ks[kt][3]
                        + v4*Ks[kt][4] + v5*Ks[kt][5] + v6*Ks[kt][6] + v7*Ks[kt][7];
                s += __shfl_xor(s, 16, 64);        // combine the two 8-dim halves
                float z = 1.f / (s + EPS_);
                union { u32x4 u; bf16x8 h; } pk;
                pk.u = u32x4{ cvt2(v0*z, v1*z), cvt2(v2*z, v3*z),
                              cvt2(v4*z, v5*z), cvt2(v6*z, v7*z) };
                bfrag[kt] = pk.h;
            }
#pragma unroll
            for (int m = 0; m < 2; ++m) {
                f32x4 acc = f32x4{bov[m][0], bov[m][1], bov[m][2], bov[m][3]};
#pragma unroll
                for (int kt = 0; kt < 4; ++kt)
                    acc = MFMA16(w2[m][kt], bfrag[kt], acc);
                long tok = tokbase + nt*16 + (l & 15);
                *(float4*)&out[tok*D + (w*2+m)*16 + (l>>4)*4] =
                    float4{acc[0], acc[1], acc[2], acc[3]};
            }
        }
    }
}

extern "C" void kernel_launch(void* const* d_in, const int* in_sizes, int n_in,
                              void* d_out, int out_size, void* d_ws, size_t ws_size,
                              hipStream_t stream) {
    (void)in_sizes; (void)n_in; (void)out_size; (void)ws_size;
    const float* Q  = (const float*)d_in[0];
    const float* Wq = (const float*)d_in[1];
    const float* bq = (const float*)d_in[2];
    const float* Wk = (const float*)d_in[3];
    const float* bk = (const float*)d_in[4];
    const float* Wv = (const float*)d_in[5];
    const float* bv = (const float*)d_in[6];
    const float* Wo = (const float*)d_in[7];
    const float* bo = (const float*)d_in[8];
    float* out = (float*)d_out;

    // ws carve (bytes): KV 64K | Ksum 4K | WB 64K | WqA 32K | W2A 256K | phiq 32M
    char* p = (char*)d_ws;
    float* KV    = (float*)p;                 p += 16384 * sizeof(float);
    float* Ksum  = (float*)p;                 p += 1024  * sizeof(float);
    short* WB    = (short*)p;                 p += 32768 * sizeof(short);
    short* WqA   = (short*)p;                 p += 16384 * sizeof(short);
    short* W2A   = (short*)p;                 p += 131072 * sizeof(short);
    u32x2* phiq  = (u32x2*)p;                 // 2048*8*4*64 slots * 8B = 32 MB

    hipMemsetAsync(d_ws, 0, (16384 + 1024)*sizeof(float), stream);
    packW <<<dim3(24),        dim3(256), 0, stream>>>(Wk, Wv, Wq, WB, WqA);
    passA <<<dim3(BS*BPB_A),  dim3(256), 0, stream>>>(Q, bk, bv, bq, WB, WqA, KV, Ksum, phiq);
    packW2<<<dim3(BS),        dim3(256), 0, stream>>>(Wo, KV, W2A);
    passB <<<dim3(BS*BPB_B),  dim3(256), 0, stream>>>(bo, W2A, Ksum, phiq, out);
}